// Round 5
// baseline (738.064 us; speedup 1.0000x reference)
//
#include <hip/hip_runtime.h>
#include <cstdint>
#include <cstddef>

#define NEG_SLOPE 0.2f

typedef _Float16 f16x8 __attribute__((ext_vector_type(8)));
typedef _Float16 f16x2 __attribute__((ext_vector_type(2)));
typedef float    f32x4 __attribute__((ext_vector_type(4)));

__device__ __forceinline__ float leaky(float x){ return x > 0.f ? x : NEG_SLOPE * x; }
__device__ __forceinline__ float elu(float x){ return x > 0.f ? x : __expf(x) - 1.f; }

// ============ split f32 -> fp16 hi + fp16 lo (hi+lo ~= exact to 2^-22) ============
__global__ void k_wcvt(const float* __restrict__ src, _Float16* __restrict__ hi,
                       _Float16* __restrict__ lo, int n)
{
    int i = blockIdx.x * 256 + threadIdx.x;
    if (i >= n) return;
    float v = src[i];
    _Float16 h = (_Float16)v;
    hi[i] = h;
    lo[i] = (_Float16)(v - (float)h);
}

// ============ fold attention vectors: w_s[h,k] = sum_c att_src[h,c] * W1[h*128+c, k] ============
__global__ __launch_bounds__(128) void k_wvec(const float* __restrict__ W1,
                                              const float* __restrict__ as1,
                                              const float* __restrict__ ad1,
                                              float* __restrict__ w_s,
                                              float* __restrict__ w_d)
{
    int h = blockIdx.x, k = threadIdx.x;
    float s = 0.f, d = 0.f;
    for (int c = 0; c < 128; ++c) {
        float w = W1[((size_t)(h * 128 + c)) * 128 + k];
        s += as1[h * 128 + c] * w;
        d += ad1[h * 128 + c] * w;
    }
    w_s[h * 128 + k] = s;
    w_d[h * 128 + k] = d;
}

// ============ layer-1 attention logits from raw x; also emit x as fp16 ============
__global__ __launch_bounds__(256) void k_attn_x(const float* __restrict__ x,
                                                const float* __restrict__ w_s,
                                                const float* __restrict__ w_d,
                                                float* __restrict__ a_s,
                                                float* __restrict__ a_d,
                                                _Float16* __restrict__ xh, int N)
{
    int n = blockIdx.x * 4 + (threadIdx.x >> 6);
    if (n >= N) return;
    int lane = threadIdx.x & 63;
    float2 xv = *(const float2*)(x + (size_t)n * 128 + lane * 2);
    f16x2 hv = { (_Float16)xv.x, (_Float16)xv.y };
    *(f16x2*)(xh + (size_t)n * 128 + lane * 2) = hv;
    float ps[4], pd[4];
    #pragma unroll
    for (int h = 0; h < 4; ++h) {
        float2 sv = *(const float2*)(w_s + h * 128 + lane * 2);
        float2 dv = *(const float2*)(w_d + h * 128 + lane * 2);
        ps[h] = xv.x * sv.x + xv.y * sv.y;
        pd[h] = xv.x * dv.x + xv.y * dv.y;
    }
    #pragma unroll
    for (int h = 0; h < 4; ++h)
        for (int off = 32; off; off >>= 1) {
            ps[h] += __shfl_xor(ps[h], off);
            pd[h] += __shfl_xor(pd[h], off);
        }
    if (lane == 0) {
        *(float4*)(a_s + (size_t)n * 4) = make_float4(ps[0], ps[1], ps[2], ps[3]);
        *(float4*)(a_d + (size_t)n * 4) = make_float4(pd[0], pd[1], pd[2], pd[3]);
    }
}

// ============ layer-2 attention logits from fp16 xh2 ============
__global__ __launch_bounds__(256) void k_attn2(const _Float16* __restrict__ xh,
                                               const float* __restrict__ as2,
                                               const float* __restrict__ ad2,
                                               float* __restrict__ a_s,
                                               float* __restrict__ a_d, int N)
{
    int n = blockIdx.x * 4 + (threadIdx.x >> 6);
    if (n >= N) return;
    int lane = threadIdx.x & 63;
    f16x2 xv = *(const f16x2*)(xh + (size_t)n * 128 + lane * 2);
    float vx = (float)xv.x, vy = (float)xv.y;
    float2 sv = *(const float2*)(as2 + lane * 2);
    float2 dv = *(const float2*)(ad2 + lane * 2);
    float ps = vx * sv.x + vy * sv.y;
    float pd = vx * dv.x + vy * dv.y;
    for (int off = 32; off; off >>= 1) { ps += __shfl_xor(ps, off); pd += __shfl_xor(pd, off); }
    if (lane == 0) { a_s[n] = ps; a_d[n] = pd; }
}

// ============ CSR construction ============
__global__ void k_count(const int* __restrict__ ei, int* __restrict__ deg, int E, int Ep)
{
    int e = blockIdx.x * blockDim.x + threadIdx.x;
    if (e >= Ep) return;
    int dst = (e < E) ? ei[E + e] : (e - E);
    atomicAdd(&deg[dst], 1);
}

__global__ __launch_bounds__(1024) void k_scanA(const int* __restrict__ deg,
                                                int* __restrict__ start,
                                                int* __restrict__ sums, int Ntot, int N)
{
    __shared__ int sm[1024];
    int tid = threadIdx.x;
    int i = blockIdx.x * 1024 + tid;
    int v = (i < N) ? deg[i] : 0;
    sm[tid] = v; __syncthreads();
    for (int off = 1; off < 1024; off <<= 1) {
        int t = (tid >= off) ? sm[tid - off] : 0;
        __syncthreads();
        sm[tid] += t;
        __syncthreads();
    }
    if (i < Ntot) start[i] = sm[tid] - v;
    if (tid == 1023) sums[blockIdx.x] = sm[1023];
}

__global__ void k_scanB(int* sums, int nb)
{
    int l = threadIdx.x;
    int v = (l < nb) ? sums[l] : 0;
    int orig = v;
    for (int off = 1; off < 64; off <<= 1) { int t = __shfl_up(v, off); if (l >= off) v += t; }
    if (l < nb) sums[l] = v - orig;
}

__global__ __launch_bounds__(1024) void k_scanC(int* __restrict__ start,
                                                const int* __restrict__ sums, int Ntot)
{
    int i = blockIdx.x * 1024 + threadIdx.x;
    if (i < Ntot) start[i] += sums[blockIdx.x];
}

__global__ void k_fill(const int* __restrict__ ei, const int* __restrict__ start,
                       int* __restrict__ cursor, int* __restrict__ csr_src, int E, int Ep)
{
    int e = blockIdx.x * blockDim.x + threadIdx.x;
    if (e >= Ep) return;
    int src, dst;
    if (e < E) { src = ei[e]; dst = ei[E + e]; } else { src = dst = e - E; }
    int pos = atomicAdd(&cursor[dst], 1);
    csr_src[start[dst] + pos] = src;
}

// ============ FUSED layer 1+2: aggregate(x) -> GEMM1(+elu) in LDS -> GEMM2 -> xh2 fp16 ============
// Block: 512 thr (8 waves), MT=64 dst nodes. LDS tile s_agg[4][64][136] fp16 (pad 136: conflict-free).
// Wave w: aggregation for dsts w*8..w*8+7 (lane covers ch 2l,2l+1, 4 heads in regs);
//         GEMM m-tile (w&3)*16, n-half (w>>2)*64. h1 overwrites s_agg in place (rows wave-... tile-ordered via barriers).
#define MT 64
__global__ __launch_bounds__(512, 4) void k_layer1(
    const int* __restrict__ start, const int* __restrict__ csr,
    const float* __restrict__ a_s, const float* __restrict__ a_d,
    const _Float16* __restrict__ xh,
    const _Float16* __restrict__ W1h, const _Float16* __restrict__ W1l,  // [512,128]
    const float* __restrict__ b1,
    const _Float16* __restrict__ W2h, const _Float16* __restrict__ W2l,  // [128,512]
    _Float16* __restrict__ xh2, int N)
{
    __shared__ __align__(16) _Float16 s_agg[4][MT][136];
    const int tid = threadIdx.x;
    const int wave = tid >> 6, lane = tid & 63;
    const int quad = lane >> 4, l16 = lane & 15;
    const int m0 = blockIdx.x * MT;

    // ---------- phase 1: softmax-weighted aggregation of fp16 x ----------
    for (int t = 0; t < 8; ++t) {
        int m = wave * 8 + t;
        int d = m0 + m;
        if (d < N) {
            int beg = start[d], end = start[d + 1];
            int deg = end - beg;
            float4 ad4 = *(const float4*)(a_d + (size_t)d * 4);
            float s0 = 0.f, s1 = 0.f, s2 = 0.f, s3 = 0.f;
            for (int i = lane; i < deg; i += 64) {
                int s = csr[beg + i];
                float4 as4 = *(const float4*)(a_s + (size_t)s * 4);
                s0 += __expf(leaky(as4.x + ad4.x));
                s1 += __expf(leaky(as4.y + ad4.y));
                s2 += __expf(leaky(as4.z + ad4.z));
                s3 += __expf(leaky(as4.w + ad4.w));
            }
            #pragma unroll
            for (int o = 32; o; o >>= 1) {
                s0 += __shfl_xor(s0, o); s1 += __shfl_xor(s1, o);
                s2 += __shfl_xor(s2, o); s3 += __shfl_xor(s3, o);
            }
            float i0 = 1.f / (s0 + 1e-16f), i1 = 1.f / (s1 + 1e-16f);
            float i2 = 1.f / (s2 + 1e-16f), i3 = 1.f / (s3 + 1e-16f);
            float a0=0.f,a1=0.f,a2=0.f,a3=0.f,a4=0.f,a5=0.f,a6=0.f,a7=0.f;
            const _Float16* xb = xh + 2 * lane;
            for (int i = 0; i < deg; ++i) {
                int s = csr[beg + i];                                 // wave-uniform
                float4 as4 = *(const float4*)(a_s + (size_t)s * 4);   // broadcast
                float w0 = __expf(leaky(as4.x + ad4.x)) * i0;
                float w1 = __expf(leaky(as4.y + ad4.y)) * i1;
                float w2 = __expf(leaky(as4.z + ad4.z)) * i2;
                float w3 = __expf(leaky(as4.w + ad4.w)) * i3;
                f16x2 hv = *(const f16x2*)(xb + (size_t)s * 128);
                float vx = (float)hv.x, vy = (float)hv.y;
                a0 += w0 * vx; a1 += w0 * vy;
                a2 += w1 * vx; a3 += w1 * vy;
                a4 += w2 * vx; a5 += w2 * vy;
                a6 += w3 * vx; a7 += w3 * vy;
            }
            f16x2 o0 = {(_Float16)a0, (_Float16)a1};
            f16x2 o1 = {(_Float16)a2, (_Float16)a3};
            f16x2 o2 = {(_Float16)a4, (_Float16)a5};
            f16x2 o3 = {(_Float16)a6, (_Float16)a7};
            *(f16x2*)&s_agg[0][m][2 * lane] = o0;
            *(f16x2*)&s_agg[1][m][2 * lane] = o1;
            *(f16x2*)&s_agg[2][m][2 * lane] = o2;
            *(f16x2*)&s_agg[3][m][2 * lane] = o3;
        } else {
            f16x2 z = {(_Float16)0.f, (_Float16)0.f};
            *(f16x2*)&s_agg[0][m][2 * lane] = z;
            *(f16x2*)&s_agg[1][m][2 * lane] = z;
            *(f16x2*)&s_agg[2][m][2 * lane] = z;
            *(f16x2*)&s_agg[3][m][2 * lane] = z;
        }
    }
    __syncthreads();

    // ---------- phase 2: GEMM1 per head, elu(h1) written back in place ----------
    const int mt = (wave & 3) * 16;
    const int nh = (wave >> 2) * 64;
    #pragma unroll
    for (int h = 0; h < 4; ++h) {
        f16x8 af[4];
        #pragma unroll
        for (int q = 0; q < 4; ++q)
            af[q] = *(const f16x8*)&s_agg[h][mt + l16][q * 32 + quad * 8];
        __syncthreads();   // all reads of s_agg[h] done before any h1 writes to it
        f32x4 acc[4] = {};
        #pragma unroll
        for (int q = 0; q < 4; ++q) {
            #pragma unroll
            for (int j = 0; j < 4; ++j) {
                int n = nh + j * 16 + l16;
                f16x8 bh = *(const f16x8*)(W1h + (size_t)(h * 128 + n) * 128 + q * 32 + quad * 8);
                f16x8 bl = *(const f16x8*)(W1l + (size_t)(h * 128 + n) * 128 + q * 32 + quad * 8);
                acc[j] = __builtin_amdgcn_mfma_f32_16x16x32_f16(af[q], bh, acc[j], 0, 0, 0);
                acc[j] = __builtin_amdgcn_mfma_f32_16x16x32_f16(af[q], bl, acc[j], 0, 0, 0);
            }
        }
        #pragma unroll
        for (int j = 0; j < 4; ++j) {
            int n = nh + j * 16 + l16;
            float bb = b1[h * 128 + n];
            #pragma unroll
            for (int r = 0; r < 4; ++r) {
                int mm = mt + quad * 4 + r;
                s_agg[h][mm][n] = (_Float16)elu(acc[j][r] + bb);
            }
        }
    }
    __syncthreads();   // h1 fully materialized in s_agg

    // ---------- phase 3: GEMM2 (K=512 spans the 4 head slots) -> xh2 fp16 ----------
    f32x4 acc2[4] = {};
    #pragma unroll
    for (int q = 0; q < 16; ++q) {
        int hh = q >> 2, qq = q & 3;
        f16x8 af = *(const f16x8*)&s_agg[hh][mt + l16][qq * 32 + quad * 8];
        #pragma unroll
        for (int j = 0; j < 4; ++j) {
            int n = nh + j * 16 + l16;
            f16x8 bh = *(const f16x8*)(W2h + (size_t)n * 512 + q * 32 + quad * 8);
            f16x8 bl = *(const f16x8*)(W2l + (size_t)n * 512 + q * 32 + quad * 8);
            acc2[j] = __builtin_amdgcn_mfma_f32_16x16x32_f16(af, bh, acc2[j], 0, 0, 0);
            acc2[j] = __builtin_amdgcn_mfma_f32_16x16x32_f16(af, bl, acc2[j], 0, 0, 0);
        }
    }
    #pragma unroll
    for (int j = 0; j < 4; ++j) {
        int n = nh + j * 16 + l16;
        #pragma unroll
        for (int r = 0; r < 4; ++r) {
            int mm = mt + quad * 4 + r;
            int d = m0 + mm;
            if (d < N) xh2[(size_t)d * 128 + n] = (_Float16)acc2[j][r];
        }
    }
}

// ============ layer-2 aggregation (fp16 gather) + bias + ELU -> h2[N,128] f32 ============
#define CAP2 256
__global__ __launch_bounds__(128) void k_agg2(const int* __restrict__ start,
                                              const int* __restrict__ csr_src,
                                              const float* __restrict__ a_s,
                                              const float* __restrict__ a_d,
                                              const _Float16* __restrict__ xh2,
                                              const float* __restrict__ b2,
                                              float* __restrict__ h2, int N)
{
    int d = blockIdx.x, tid = threadIdx.x;
    __shared__ float s_alpha[CAP2];
    __shared__ int   s_src[CAP2];
    __shared__ float red[128];
    __shared__ float s_invs;

    int beg = start[d], end = start[d + 1];
    int deg = end - beg;
    float ad = a_d[d];
    float ps = 0.f;
    for (int i = tid; i < deg; i += 128) {
        int s = csr_src[beg + i];
        float e = __expf(leaky(a_s[s] + ad));
        ps += e;
        if (i < CAP2) { s_src[i] = s; s_alpha[i] = e; }
    }
    red[tid] = ps; __syncthreads();
    for (int st = 64; st > 0; st >>= 1) { if (tid < st) red[tid] += red[tid + st]; __syncthreads(); }
    if (tid == 0) s_invs = 1.f / (red[0] + 1e-16f);
    __syncthreads();
    float inv = s_invs;
    float acc = 0.f;
    for (int i = 0; i < deg; ++i) {
        float al; int s;
        if (i < CAP2) { al = s_alpha[i] * inv; s = s_src[i]; }
        else { s = csr_src[beg + i]; al = __expf(leaky(a_s[s] + ad)) * inv; }
        acc += al * (float)xh2[(size_t)s * 128 + tid];
    }
    h2[(size_t)d * 128 + tid] = elu(acc + b2[tid]);
}

// ============ graph boundaries from SORTED batch ============
__global__ void k_gbound(const int* __restrict__ batch, int* __restrict__ gstart, int N, int G)
{
    int n = blockIdx.x * blockDim.x + threadIdx.x;
    if (n >= N) return;
    int b = batch[n];
    int prev = (n == 0) ? -1 : batch[n - 1];
    for (int g = prev + 1; g <= b; ++g) gstart[g] = n;
    if (n == N - 1)
        for (int g = b + 1; g <= G; ++g) gstart[g] = N;
}

// ============ pooling stage A: chunked partial sums ============
#define PCH 64
__global__ __launch_bounds__(128) void k_poolA(const float* __restrict__ h2,
                                               const int* __restrict__ batch,
                                               float* __restrict__ pooled, int N)
{
    int c = threadIdx.x;
    int n0 = blockIdx.x * PCH;
    int n1 = n0 + PCH < N ? n0 + PCH : N;
    if (n0 >= N) return;
    int g = batch[n0];
    float acc = 0.f;
    for (int n = n0; n < n1; ++n) {
        int bg = batch[n];
        if (bg != g) { atomicAdd(&pooled[(size_t)g * 128 + c], acc); acc = 0.f; g = bg; }
        acc += h2[(size_t)n * 128 + c];
    }
    atomicAdd(&pooled[(size_t)g * 128 + c], acc);
}

// ============ head: mean + relu(pooled@Wh1^T+bh1) @ Wh2^T + bh2 ============
__global__ __launch_bounds__(128) void k_head(const float* __restrict__ pooled,
                                              const int* __restrict__ gstart,
                                              const float* __restrict__ Wh1,
                                              const float* __restrict__ bh1,
                                              const float* __restrict__ Wh2,
                                              const float* __restrict__ bh2,
                                              float* __restrict__ out)
{
    int g = blockIdx.x, c = threadIdx.x;
    __shared__ float p[128];
    __shared__ float red[128];
    float cf = (float)(gstart[g + 1] - gstart[g]); cf = cf > 1.f ? cf : 1.f;
    p[c] = pooled[(size_t)g * 128 + c] / cf;
    __syncthreads();
    float z = bh1[c];
    for (int k = 0; k < 128; ++k) z += p[k] * Wh1[c * 128 + k];
    z = z > 0.f ? z : 0.f;
    red[c] = z * Wh2[c];
    __syncthreads();
    for (int st = 64; st > 0; st >>= 1) { if (c < st) red[c] += red[c + st]; __syncthreads(); }
    if (c == 0) out[g] = red[0] + bh2[0];
}

// ============ launch ============
extern "C" void kernel_launch(void* const* d_in, const int* in_sizes, int n_in,
                              void* d_out, int out_size, void* d_ws, size_t ws_size,
                              hipStream_t stream)
{
    const float* x   = (const float*)d_in[0];
    const int*   ei  = (const int*)d_in[1];
    const int*   bat = (const int*)d_in[2];
    const float* W1  = (const float*)d_in[3];
    const float* as1 = (const float*)d_in[4];
    const float* ad1 = (const float*)d_in[5];
    const float* b1  = (const float*)d_in[6];
    const float* W2  = (const float*)d_in[7];
    const float* as2 = (const float*)d_in[8];
    const float* ad2 = (const float*)d_in[9];
    const float* b2  = (const float*)d_in[10];
    const float* Wh1 = (const float*)d_in[11];
    const float* bh1 = (const float*)d_in[12];
    const float* Wh2 = (const float*)d_in[13];
    const float* bh2 = (const float*)d_in[14];
    float* out = (float*)d_out;

    const int N  = in_sizes[0] / 128;
    const int E  = in_sizes[1] / 2;
    const int Ep = E + N;
    const int G  = 128;

    char* w = (char*)d_ws;
    size_t off = 0;
    auto alloc = [&](size_t bytes) -> char* {
        char* p = w + off; off += (bytes + 511) & ~(size_t)511; return p;
    };
    _Float16* x_h  = (_Float16*)alloc((size_t)N * 128 * 2);
    _Float16* xh2h = (_Float16*)alloc((size_t)N * 128 * 2);
    float*    h2   = (float*)alloc((size_t)N * 128 * 4);
    float*    As1  = (float*)alloc((size_t)N * 4 * 4);
    float*    Ad1  = (float*)alloc((size_t)N * 4 * 4);
    float*    As2  = (float*)alloc((size_t)N * 4);
    float*    Ad2  = (float*)alloc((size_t)N * 4);
    float*    w_s1 = (float*)alloc(512 * 4);
    float*    w_d1 = (float*)alloc(512 * 4);
    _Float16* W1hi = (_Float16*)alloc(65536 * 2);
    _Float16* W1lo = (_Float16*)alloc(65536 * 2);
    _Float16* W2hi = (_Float16*)alloc(65536 * 2);
    _Float16* W2lo = (_Float16*)alloc(65536 * 2);
    int* startb = (int*)alloc((size_t)(N + 1) * 4);
    int* csr    = (int*)alloc((size_t)Ep * 4);
    int* sums   = (int*)alloc(4096);
    int* gstart = (int*)alloc((size_t)(G + 1) * 4);
    char* zbase = w + off;                                // zero-init group
    int*   deg    = (int*)alloc((size_t)N * 4);
    int*   cursor = (int*)alloc((size_t)N * 4);
    float* pooled = (float*)alloc((size_t)G * 128 * 4);
    size_t zbytes = (size_t)((w + off) - zbase);

    hipMemsetAsync(zbase, 0, zbytes, stream);

    // 1) fold attention vectors; logits + fp16 x
    k_wvec<<<4, 128, 0, stream>>>(W1, as1, ad1, w_s1, w_d1);
    k_attn_x<<<(N + 3) / 4, 256, 0, stream>>>(x, w_s1, w_d1, As1, Ad1, x_h, N);
    // 2) weights -> split fp16
    k_wcvt<<<256, 256, 0, stream>>>(W1, W1hi, W1lo, 65536);
    k_wcvt<<<256, 256, 0, stream>>>(W2, W2hi, W2lo, 65536);
    // 3) CSR by destination (self-loops appended)
    k_count<<<(Ep + 255) / 256, 256, 0, stream>>>(ei, deg, E, Ep);
    int nb = (N + 1 + 1023) / 1024;
    k_scanA<<<nb, 1024, 0, stream>>>(deg, startb, sums, N + 1, N);
    k_scanB<<<1, 64, 0, stream>>>(sums, nb);
    k_scanC<<<nb, 1024, 0, stream>>>(startb, sums, N + 1);
    k_fill<<<(Ep + 255) / 256, 256, 0, stream>>>(ei, startb, cursor, csr, E, Ep);
    // 4) graph boundaries
    k_gbound<<<(N + 255) / 256, 256, 0, stream>>>(bat, gstart, N, G);
    // 5) fused aggregate + GEMM1(+elu) + GEMM2 -> xh2 fp16
    k_layer1<<<(N + MT - 1) / MT, 512, 0, stream>>>(
        startb, csr, As1, Ad1, x_h, W1hi, W1lo, b1, W2hi, W2lo, xh2h, N);
    // 6) layer-2 attention logits
    k_attn2<<<(N + 3) / 4, 256, 0, stream>>>(xh2h, as2, ad2, As2, Ad2, N);
    // 7) layer-2 aggregation + bias + ELU -> h2 f32
    k_agg2<<<N, 128, 0, stream>>>(startb, csr, As2, Ad2, xh2h, b2, h2, N);
    // 8) two-stage pooling + MLP head
    k_poolA<<<(N + PCH - 1) / PCH, 128, 0, stream>>>(h2, bat, pooled, N);
    k_head<<<G, 128, 0, stream>>>(pooled, gstart, Wh1, bh1, Wh2, bh2, out);
}

// Round 6
// 484.199 us; speedup vs baseline: 1.5243x; 1.5243x over previous
//
#include <hip/hip_runtime.h>
#include <cstdint>
#include <cstddef>

#define NEG_SLOPE 0.2f

typedef _Float16 f16x8 __attribute__((ext_vector_type(8)));
typedef _Float16 f16x2 __attribute__((ext_vector_type(2)));
typedef float    f32x4 __attribute__((ext_vector_type(4)));

__device__ __forceinline__ float leaky(float x){ return x > 0.f ? x : NEG_SLOPE * x; }
__device__ __forceinline__ float elu(float x){ return x > 0.f ? x : __expf(x) - 1.f; }

// ============ split f32 -> fp16 hi + fp16 lo ============
__global__ void k_wcvt(const float* __restrict__ src, _Float16* __restrict__ hi,
                       _Float16* __restrict__ lo, int n)
{
    int i = blockIdx.x * 256 + threadIdx.x;
    if (i >= n) return;
    float v = src[i];
    _Float16 h = (_Float16)v;
    hi[i] = h;
    lo[i] = (_Float16)(v - (float)h);
}

// ============ fp16-A x split-fp16-B MFMA GEMM: C[m,n] = sum_k A[m,k]*B[n,k], n-dim = 128 ====
// block 256 thr (4 waves 2x2), tile 128x128, BK=32. z-dim = independent sub-GEMMs (heads).
// B split hi/lo (pre-converted): a*b ~= a*bh + a*bl. A is fp16 (already-rounded data).
template<bool FUSE_BIAS_ELU>
__global__ __launch_bounds__(256, 2) void k_gemm_h(
    const _Float16* __restrict__ A, const _Float16* __restrict__ Bh,
    const _Float16* __restrict__ Bl, const float* __restrict__ bias,
    _Float16* __restrict__ C,
    int M, int K, int lda, int ldb, int ldc,
    long aZ, long bZ, long cZ, long biasZ)
{
    constexpr int LS = 40;   // halfs per LDS row (32 + 8 pad)
    __shared__ __align__(16) _Float16 As [128 * LS];
    __shared__ __align__(16) _Float16 Bhs[128 * LS];
    __shared__ __align__(16) _Float16 Bls[128 * LS];

    const _Float16* Ab  = A  + (size_t)blockIdx.z * aZ;
    const _Float16* Bhb = Bh + (size_t)blockIdx.z * bZ;
    const _Float16* Blb = Bl + (size_t)blockIdx.z * bZ;
    _Float16* Cb = C + (size_t)blockIdx.z * cZ;

    const int tid = threadIdx.x;
    const int wave = tid >> 6, lane = tid & 63;
    const int wm = wave >> 1, wn = wave & 1;
    const int quad = lane >> 4, l16 = lane & 15;
    const int m0 = blockIdx.x * 128;

    f32x4 acc[4][4] = {};

    for (int k0 = 0; k0 < K; k0 += 32) {
        #pragma unroll
        for (int q = 0; q < 2; ++q) {
            int idx = tid + q * 256;            // 0..511: row 0..127, kq 0..3
            int row = idx >> 2, kq = idx & 3;
            int rg = m0 + row;
            f16x8 va = {};
            if (rg < M) va = *(const f16x8*)(Ab + (size_t)rg * lda + k0 + kq * 8);
            *(f16x8*)&As[row * LS + kq * 8] = va;
            *(f16x8*)&Bhs[row * LS + kq * 8] = *(const f16x8*)(Bhb + (size_t)row * ldb + k0 + kq * 8);
            *(f16x8*)&Bls[row * LS + kq * 8] = *(const f16x8*)(Blb + (size_t)row * ldb + k0 + kq * 8);
        }
        __syncthreads();

        f16x8 af[4], bhf[4], blf[4];
        #pragma unroll
        for (int i = 0; i < 4; ++i) {
            int mr = wm * 64 + i * 16 + l16;
            af[i] = *(const f16x8*)&As[mr * LS + quad * 8];
            int nr = wn * 64 + i * 16 + l16;
            bhf[i] = *(const f16x8*)&Bhs[nr * LS + quad * 8];
            blf[i] = *(const f16x8*)&Bls[nr * LS + quad * 8];
        }
        #pragma unroll
        for (int i = 0; i < 4; ++i)
            #pragma unroll
            for (int j = 0; j < 4; ++j) {
                acc[i][j] = __builtin_amdgcn_mfma_f32_16x16x32_f16(af[i], bhf[j], acc[i][j], 0, 0, 0);
                acc[i][j] = __builtin_amdgcn_mfma_f32_16x16x32_f16(af[i], blf[j], acc[i][j], 0, 0, 0);
            }
        __syncthreads();
    }

    #pragma unroll
    for (int j = 0; j < 4; ++j) {
        int n = wn * 64 + j * 16 + l16;
        float bb = 0.f;
        if (FUSE_BIAS_ELU) bb = bias[blockIdx.z * biasZ + n];
        #pragma unroll
        for (int i = 0; i < 4; ++i)
            #pragma unroll
            for (int r = 0; r < 4; ++r) {
                int m = m0 + wm * 64 + i * 16 + quad * 4 + r;
                if (m < M) {
                    float v = acc[i][j][r];
                    if (FUSE_BIAS_ELU) v = elu(v + bb);
                    Cb[(size_t)m * ldc + n] = (_Float16)v;
                }
            }
    }
}

// ============ fold attention vectors: w_s[h,k] = sum_c att_src[h,c] * W1[h*128+c, k] ============
__global__ __launch_bounds__(128) void k_wvec(const float* __restrict__ W1,
                                              const float* __restrict__ as1,
                                              const float* __restrict__ ad1,
                                              float* __restrict__ w_s,
                                              float* __restrict__ w_d)
{
    int h = blockIdx.x, k = threadIdx.x;
    float s = 0.f, d = 0.f;
    for (int c = 0; c < 128; ++c) {
        float w = W1[((size_t)(h * 128 + c)) * 128 + k];
        s += as1[h * 128 + c] * w;
        d += ad1[h * 128 + c] * w;
    }
    w_s[h * 128 + k] = s;
    w_d[h * 128 + k] = d;
}

// ============ layer-1 attention logits from raw x; also emit x as fp16 ============
__global__ __launch_bounds__(256) void k_attn_x(const float* __restrict__ x,
                                                const float* __restrict__ w_s,
                                                const float* __restrict__ w_d,
                                                float* __restrict__ a_s,
                                                float* __restrict__ a_d,
                                                _Float16* __restrict__ xh, int N)
{
    int n = blockIdx.x * 4 + (threadIdx.x >> 6);
    if (n >= N) return;
    int lane = threadIdx.x & 63;
    float2 xv = *(const float2*)(x + (size_t)n * 128 + lane * 2);
    f16x2 hv = { (_Float16)xv.x, (_Float16)xv.y };
    *(f16x2*)(xh + (size_t)n * 128 + lane * 2) = hv;
    float ps[4], pd[4];
    #pragma unroll
    for (int h = 0; h < 4; ++h) {
        float2 sv = *(const float2*)(w_s + h * 128 + lane * 2);
        float2 dv = *(const float2*)(w_d + h * 128 + lane * 2);
        ps[h] = xv.x * sv.x + xv.y * sv.y;
        pd[h] = xv.x * dv.x + xv.y * dv.y;
    }
    #pragma unroll
    for (int h = 0; h < 4; ++h)
        for (int off = 32; off; off >>= 1) {
            ps[h] += __shfl_xor(ps[h], off);
            pd[h] += __shfl_xor(pd[h], off);
        }
    if (lane == 0) {
        *(float4*)(a_s + (size_t)n * 4) = make_float4(ps[0], ps[1], ps[2], ps[3]);
        *(float4*)(a_d + (size_t)n * 4) = make_float4(pd[0], pd[1], pd[2], pd[3]);
    }
}

// ============ layer-2 attention logits from fp16 xh2 ============
__global__ __launch_bounds__(256) void k_attn2(const _Float16* __restrict__ xh,
                                               const float* __restrict__ as2,
                                               const float* __restrict__ ad2,
                                               float* __restrict__ a_s,
                                               float* __restrict__ a_d, int N)
{
    int n = blockIdx.x * 4 + (threadIdx.x >> 6);
    if (n >= N) return;
    int lane = threadIdx.x & 63;
    f16x2 xv = *(const f16x2*)(xh + (size_t)n * 128 + lane * 2);
    float vx = (float)xv.x, vy = (float)xv.y;
    float2 sv = *(const float2*)(as2 + lane * 2);
    float2 dv = *(const float2*)(ad2 + lane * 2);
    float ps = vx * sv.x + vy * sv.y;
    float pd = vx * dv.x + vy * dv.y;
    for (int off = 32; off; off >>= 1) { ps += __shfl_xor(ps, off); pd += __shfl_xor(pd, off); }
    if (lane == 0) { a_s[n] = ps; a_d[n] = pd; }
}

// ============ CSR construction ============
__global__ void k_count(const int* __restrict__ ei, int* __restrict__ deg, int E, int Ep)
{
    int e = blockIdx.x * blockDim.x + threadIdx.x;
    if (e >= Ep) return;
    int dst = (e < E) ? ei[E + e] : (e - E);
    atomicAdd(&deg[dst], 1);
}

__global__ __launch_bounds__(1024) void k_scanA(const int* __restrict__ deg,
                                                int* __restrict__ start,
                                                int* __restrict__ sums, int Ntot, int N)
{
    __shared__ int sm[1024];
    int tid = threadIdx.x;
    int i = blockIdx.x * 1024 + tid;
    int v = (i < N) ? deg[i] : 0;
    sm[tid] = v; __syncthreads();
    for (int off = 1; off < 1024; off <<= 1) {
        int t = (tid >= off) ? sm[tid - off] : 0;
        __syncthreads();
        sm[tid] += t;
        __syncthreads();
    }
    if (i < Ntot) start[i] = sm[tid] - v;
    if (tid == 1023) sums[blockIdx.x] = sm[1023];
}

__global__ void k_scanB(int* sums, int nb)
{
    int l = threadIdx.x;
    int v = (l < nb) ? sums[l] : 0;
    int orig = v;
    for (int off = 1; off < 64; off <<= 1) { int t = __shfl_up(v, off); if (l >= off) v += t; }
    if (l < nb) sums[l] = v - orig;
}

__global__ __launch_bounds__(1024) void k_scanC(int* __restrict__ start,
                                                const int* __restrict__ sums, int Ntot)
{
    int i = blockIdx.x * 1024 + threadIdx.x;
    if (i < Ntot) start[i] += sums[blockIdx.x];
}

__global__ void k_fill(const int* __restrict__ ei, const int* __restrict__ start,
                       int* __restrict__ cursor, int* __restrict__ csr_src, int E, int Ep)
{
    int e = blockIdx.x * blockDim.x + threadIdx.x;
    if (e >= Ep) return;
    int src, dst;
    if (e < E) { src = ei[e]; dst = ei[E + e]; } else { src = dst = e - E; }
    int pos = atomicAdd(&cursor[dst], 1);
    csr_src[start[dst] + pos] = src;
}

// ============ layer-1 aggregation over fp16 x (128-dim), 4 heads -> agg fp16 [N,512] ============
#define CAPA 256
__global__ __launch_bounds__(128) void k_agg1x(const int* __restrict__ start,
                                               const int* __restrict__ csr_src,
                                               const float* __restrict__ a_s,
                                               const float* __restrict__ a_d,
                                               const _Float16* __restrict__ x,
                                               _Float16* __restrict__ agg, int N)
{
    int d = blockIdx.x, tid = threadIdx.x;
    __shared__ float s_al[CAPA * 4];
    __shared__ int   s_src[CAPA];
    __shared__ float red[4 * 128];
    __shared__ float s_inv[4];

    int beg = start[d], end = start[d + 1];
    int deg = end - beg;
    float4 ad4 = *(const float4*)(a_d + (size_t)d * 4);

    float ps0 = 0, ps1 = 0, ps2 = 0, ps3 = 0;
    for (int i = tid; i < deg; i += 128) {
        int s = csr_src[beg + i];
        float4 as4 = *(const float4*)(a_s + (size_t)s * 4);
        float e0 = __expf(leaky(as4.x + ad4.x));
        float e1 = __expf(leaky(as4.y + ad4.y));
        float e2 = __expf(leaky(as4.z + ad4.z));
        float e3 = __expf(leaky(as4.w + ad4.w));
        ps0 += e0; ps1 += e1; ps2 += e2; ps3 += e3;
        if (i < CAPA) { s_src[i] = s; *(float4*)&s_al[i*4] = make_float4(e0, e1, e2, e3); }
    }
    red[tid] = ps0; red[128+tid] = ps1; red[256+tid] = ps2; red[384+tid] = ps3;
    __syncthreads();
    for (int st = 64; st > 0; st >>= 1) {
        if (tid < st) {
            red[tid]     += red[tid+st];
            red[128+tid] += red[128+tid+st];
            red[256+tid] += red[256+tid+st];
            red[384+tid] += red[384+tid+st];
        }
        __syncthreads();
    }
    if (tid < 4) s_inv[tid] = 1.f / (red[tid*128] + 1e-16f);
    __syncthreads();
    int ncap4 = (deg < CAPA ? deg : CAPA) * 4;
    for (int j = tid; j < ncap4; j += 128) s_al[j] *= s_inv[j & 3];
    __syncthreads();

    float inv0 = s_inv[0], inv1 = s_inv[1], inv2 = s_inv[2], inv3 = s_inv[3];
    int c = tid;
    float acc0 = 0.f, acc1 = 0.f, acc2 = 0.f, acc3 = 0.f;
    for (int i = 0; i < deg; ++i) {
        float4 al; int s;
        if (i < CAPA) { al = *(const float4*)&s_al[i*4]; s = s_src[i]; }
        else {
            s = csr_src[beg + i];
            float4 as4 = *(const float4*)(a_s + (size_t)s * 4);
            al.x = __expf(leaky(as4.x + ad4.x)) * inv0;
            al.y = __expf(leaky(as4.y + ad4.y)) * inv1;
            al.z = __expf(leaky(as4.z + ad4.z)) * inv2;
            al.w = __expf(leaky(as4.w + ad4.w)) * inv3;
        }
        float xv = (float)x[(size_t)s * 128 + c];
        acc0 += al.x * xv; acc1 += al.y * xv; acc2 += al.z * xv; acc3 += al.w * xv;
    }
    _Float16* o = agg + (size_t)d * 512 + c;
    o[0]   = (_Float16)acc0;
    o[128] = (_Float16)acc1;
    o[256] = (_Float16)acc2;
    o[384] = (_Float16)acc3;
}

// ============ layer-2 aggregation (fp16 gather) + bias + ELU -> h2[N,128] f32 ============
#define CAP2 256
__global__ __launch_bounds__(128) void k_agg2(const int* __restrict__ start,
                                              const int* __restrict__ csr_src,
                                              const float* __restrict__ a_s,
                                              const float* __restrict__ a_d,
                                              const _Float16* __restrict__ xh2,
                                              const float* __restrict__ b2,
                                              float* __restrict__ h2, int N)
{
    int d = blockIdx.x, tid = threadIdx.x;
    __shared__ float s_alpha[CAP2];
    __shared__ int   s_src[CAP2];
    __shared__ float red[128];
    __shared__ float s_invs;

    int beg = start[d], end = start[d + 1];
    int deg = end - beg;
    float ad = a_d[d];
    float ps = 0.f;
    for (int i = tid; i < deg; i += 128) {
        int s = csr_src[beg + i];
        float e = __expf(leaky(a_s[s] + ad));
        ps += e;
        if (i < CAP2) { s_src[i] = s; s_alpha[i] = e; }
    }
    red[tid] = ps; __syncthreads();
    for (int st = 64; st > 0; st >>= 1) { if (tid < st) red[tid] += red[tid + st]; __syncthreads(); }
    if (tid == 0) s_invs = 1.f / (red[0] + 1e-16f);
    __syncthreads();
    float inv = s_invs;
    float acc = 0.f;
    for (int i = 0; i < deg; ++i) {
        float al; int s;
        if (i < CAP2) { al = s_alpha[i] * inv; s = s_src[i]; }
        else { s = csr_src[beg + i]; al = __expf(leaky(a_s[s] + ad)) * inv; }
        acc += al * (float)xh2[(size_t)s * 128 + tid];
    }
    h2[(size_t)d * 128 + tid] = elu(acc + b2[tid]);
}

// ============ graph boundaries from SORTED batch ============
__global__ void k_gbound(const int* __restrict__ batch, int* __restrict__ gstart, int N, int G)
{
    int n = blockIdx.x * blockDim.x + threadIdx.x;
    if (n >= N) return;
    int b = batch[n];
    int prev = (n == 0) ? -1 : batch[n - 1];
    for (int g = prev + 1; g <= b; ++g) gstart[g] = n;
    if (n == N - 1)
        for (int g = b + 1; g <= G; ++g) gstart[g] = N;
}

// ============ pooling stage A: chunked partial sums ============
#define PCH 64
__global__ __launch_bounds__(128) void k_poolA(const float* __restrict__ h2,
                                               const int* __restrict__ batch,
                                               float* __restrict__ pooled, int N)
{
    int c = threadIdx.x;
    int n0 = blockIdx.x * PCH;
    int n1 = n0 + PCH < N ? n0 + PCH : N;
    if (n0 >= N) return;
    int g = batch[n0];
    float acc = 0.f;
    for (int n = n0; n < n1; ++n) {
        int bg = batch[n];
        if (bg != g) { atomicAdd(&pooled[(size_t)g * 128 + c], acc); acc = 0.f; g = bg; }
        acc += h2[(size_t)n * 128 + c];
    }
    atomicAdd(&pooled[(size_t)g * 128 + c], acc);
}

// ============ head: mean + relu(pooled@Wh1^T+bh1) @ Wh2^T + bh2 ============
__global__ __launch_bounds__(128) void k_head(const float* __restrict__ pooled,
                                              const int* __restrict__ gstart,
                                              const float* __restrict__ Wh1,
                                              const float* __restrict__ bh1,
                                              const float* __restrict__ Wh2,
                                              const float* __restrict__ bh2,
                                              float* __restrict__ out)
{
    int g = blockIdx.x, c = threadIdx.x;
    __shared__ float p[128];
    __shared__ float red[128];
    float cf = (float)(gstart[g + 1] - gstart[g]); cf = cf > 1.f ? cf : 1.f;
    p[c] = pooled[(size_t)g * 128 + c] / cf;
    __syncthreads();
    float z = bh1[c];
    for (int k = 0; k < 128; ++k) z += p[k] * Wh1[c * 128 + k];
    z = z > 0.f ? z : 0.f;
    red[c] = z * Wh2[c];
    __syncthreads();
    for (int st = 64; st > 0; st >>= 1) { if (c < st) red[c] += red[c + st]; __syncthreads(); }
    if (c == 0) out[g] = red[0] + bh2[0];
}

// ============ launch ============
extern "C" void kernel_launch(void* const* d_in, const int* in_sizes, int n_in,
                              void* d_out, int out_size, void* d_ws, size_t ws_size,
                              hipStream_t stream)
{
    const float* x   = (const float*)d_in[0];
    const int*   ei  = (const int*)d_in[1];
    const int*   bat = (const int*)d_in[2];
    const float* W1  = (const float*)d_in[3];
    const float* as1 = (const float*)d_in[4];
    const float* ad1 = (const float*)d_in[5];
    const float* b1  = (const float*)d_in[6];
    const float* W2  = (const float*)d_in[7];
    const float* as2 = (const float*)d_in[8];
    const float* ad2 = (const float*)d_in[9];
    const float* b2  = (const float*)d_in[10];
    const float* Wh1 = (const float*)d_in[11];
    const float* bh1 = (const float*)d_in[12];
    const float* Wh2 = (const float*)d_in[13];
    const float* bh2 = (const float*)d_in[14];
    float* out = (float*)d_out;

    const int N  = in_sizes[0] / 128;
    const int E  = in_sizes[1] / 2;
    const int Ep = E + N;
    const int G  = 128;

    char* w = (char*)d_ws;
    size_t off = 0;
    auto alloc = [&](size_t bytes) -> char* {
        char* p = w + off; off += (bytes + 511) & ~(size_t)511; return p;
    };
    _Float16* x_h  = (_Float16*)alloc((size_t)N * 128 * 2);
    _Float16* agg  = (_Float16*)alloc((size_t)N * 512 * 2);   // reused as nothing else
    _Float16* h1   = (_Float16*)alloc((size_t)N * 512 * 2);
    _Float16* xh2h = (_Float16*)alloc((size_t)N * 128 * 2);
    float*    h2   = (float*)alloc((size_t)N * 128 * 4);
    float*    As1  = (float*)alloc((size_t)N * 4 * 4);
    float*    Ad1  = (float*)alloc((size_t)N * 4 * 4);
    float*    As2  = (float*)alloc((size_t)N * 4);
    float*    Ad2  = (float*)alloc((size_t)N * 4);
    float*    w_s1 = (float*)alloc(512 * 4);
    float*    w_d1 = (float*)alloc(512 * 4);
    _Float16* W1hi = (_Float16*)alloc(65536 * 2);
    _Float16* W1lo = (_Float16*)alloc(65536 * 2);
    _Float16* W2hi = (_Float16*)alloc(65536 * 2);
    _Float16* W2lo = (_Float16*)alloc(65536 * 2);
    int* startb = (int*)alloc((size_t)(N + 1) * 4);
    int* csr    = (int*)alloc((size_t)Ep * 4);
    int* sums   = (int*)alloc(4096);
    int* gstart = (int*)alloc((size_t)(G + 1) * 4);
    char* zbase = w + off;                                // zero-init group
    int*   deg    = (int*)alloc((size_t)N * 4);
    int*   cursor = (int*)alloc((size_t)N * 4);
    float* pooled = (float*)alloc((size_t)G * 128 * 4);
    size_t zbytes = (size_t)((w + off) - zbase);

    hipMemsetAsync(zbase, 0, zbytes, stream);

    // 1) fold attention vectors; logits + fp16 x
    k_wvec<<<4, 128, 0, stream>>>(W1, as1, ad1, w_s1, w_d1);
    k_attn_x<<<(N + 3) / 4, 256, 0, stream>>>(x, w_s1, w_d1, As1, Ad1, x_h, N);
    // 2) weights -> split fp16
    k_wcvt<<<256, 256, 0, stream>>>(W1, W1hi, W1lo, 65536);
    k_wcvt<<<256, 256, 0, stream>>>(W2, W2hi, W2lo, 65536);
    // 3) CSR by destination (self-loops appended)
    k_count<<<(Ep + 255) / 256, 256, 0, stream>>>(ei, deg, E, Ep);
    int nb = (N + 1 + 1023) / 1024;
    k_scanA<<<nb, 1024, 0, stream>>>(deg, startb, sums, N + 1, N);
    k_scanB<<<1, 64, 0, stream>>>(sums, nb);
    k_scanC<<<nb, 1024, 0, stream>>>(startb, sums, N + 1);
    k_fill<<<(Ep + 255) / 256, 256, 0, stream>>>(ei, startb, cursor, csr, E, Ep);
    // 4) graph boundaries
    k_gbound<<<(N + 255) / 256, 256, 0, stream>>>(bat, gstart, N, G);
    // 5) layer-1 aggregation over fp16 x -> agg fp16 [N, 4*128]
    k_agg1x<<<N, 128, 0, stream>>>(startb, csr, As1, Ad1, x_h, agg, N);
    // 6) block-diag projection + bias + ELU (fp16 MFMA): h1_h = elu(agg_h @ W1_h^T + b1_h)
    k_gemm_h<true><<<dim3((N + 127) / 128, 1, 4), 256, 0, stream>>>(
        agg, W1hi, W1lo, b1, h1, N, 128, 512, 128, 512, 128L, 16384L, 128L, 128L);
    // 7) xh2 = h1 @ W2^T  [N,128]  (fp16 MFMA)
    k_gemm_h<false><<<dim3((N + 127) / 128, 1, 1), 256, 0, stream>>>(
        h1, W2hi, W2lo, nullptr, xh2h, N, 512, 512, 512, 128, 0L, 0L, 0L, 0L);
    // 8) layer-2 attention logits
    k_attn2<<<(N + 3) / 4, 256, 0, stream>>>(xh2h, as2, ad2, As2, Ad2, N);
    // 9) layer-2 aggregation + bias + ELU -> h2 f32
    k_agg2<<<N, 128, 0, stream>>>(startb, csr, As2, Ad2, xh2h, b2, h2, N);
    // 10) two-stage pooling + MLP head
    k_poolA<<<(N + PCH - 1) / PCH, 128, 0, stream>>>(h2, bat, pooled, N);
    k_head<<<G, 128, 0, stream>>>(pooled, gstart, Wh1, bh1, Wh2, bh2, out);
}

// Round 7
// 460.860 us; speedup vs baseline: 1.6015x; 1.0506x over previous
//
#include <hip/hip_runtime.h>
#include <cstdint>
#include <cstddef>

#define NEG_SLOPE 0.2f

typedef _Float16 f16x8 __attribute__((ext_vector_type(8)));
typedef _Float16 f16x2 __attribute__((ext_vector_type(2)));
typedef float    f32x4 __attribute__((ext_vector_type(4)));

__device__ __forceinline__ float leaky(float x){ return x > 0.f ? x : NEG_SLOPE * x; }
__device__ __forceinline__ float elu(float x){ return x > 0.f ? x : __expf(x) - 1.f; }

// ============ split f32 -> fp16 hi + fp16 lo ============
__global__ void k_wcvt(const float* __restrict__ src, _Float16* __restrict__ hi,
                       _Float16* __restrict__ lo, int n)
{
    int i = blockIdx.x * 256 + threadIdx.x;
    if (i >= n) return;
    float v = src[i];
    _Float16 h = (_Float16)v;
    hi[i] = h;
    lo[i] = (_Float16)(v - (float)h);
}

// ============ fp16-A x split-fp16-B MFMA GEMM (tile 128x128, BK=32, z = heads) ============
template<bool FUSE_BIAS_ELU>
__global__ __launch_bounds__(256, 2) void k_gemm_h(
    const _Float16* __restrict__ A, const _Float16* __restrict__ Bh,
    const _Float16* __restrict__ Bl, const float* __restrict__ bias,
    _Float16* __restrict__ C,
    int M, int K, int lda, int ldb, int ldc,
    long aZ, long bZ, long cZ, long biasZ)
{
    constexpr int LS = 40;   // halfs per LDS row (32 + 8 pad)
    __shared__ __align__(16) _Float16 As [128 * LS];
    __shared__ __align__(16) _Float16 Bhs[128 * LS];
    __shared__ __align__(16) _Float16 Bls[128 * LS];

    const _Float16* Ab  = A  + (size_t)blockIdx.z * aZ;
    const _Float16* Bhb = Bh + (size_t)blockIdx.z * bZ;
    const _Float16* Blb = Bl + (size_t)blockIdx.z * bZ;
    _Float16* Cb = C + (size_t)blockIdx.z * cZ;

    const int tid = threadIdx.x;
    const int wave = tid >> 6, lane = tid & 63;
    const int wm = wave >> 1, wn = wave & 1;
    const int quad = lane >> 4, l16 = lane & 15;
    const int m0 = blockIdx.x * 128;

    f32x4 acc[4][4] = {};

    for (int k0 = 0; k0 < K; k0 += 32) {
        #pragma unroll
        for (int q = 0; q < 2; ++q) {
            int idx = tid + q * 256;            // 0..511: row 0..127, kq 0..3
            int row = idx >> 2, kq = idx & 3;
            int rg = m0 + row;
            f16x8 va = {};
            if (rg < M) va = *(const f16x8*)(Ab + (size_t)rg * lda + k0 + kq * 8);
            *(f16x8*)&As[row * LS + kq * 8] = va;
            *(f16x8*)&Bhs[row * LS + kq * 8] = *(const f16x8*)(Bhb + (size_t)row * ldb + k0 + kq * 8);
            *(f16x8*)&Bls[row * LS + kq * 8] = *(const f16x8*)(Blb + (size_t)row * ldb + k0 + kq * 8);
        }
        __syncthreads();

        f16x8 af[4], bhf[4], blf[4];
        #pragma unroll
        for (int i = 0; i < 4; ++i) {
            int mr = wm * 64 + i * 16 + l16;
            af[i] = *(const f16x8*)&As[mr * LS + quad * 8];
            int nr = wn * 64 + i * 16 + l16;
            bhf[i] = *(const f16x8*)&Bhs[nr * LS + quad * 8];
            blf[i] = *(const f16x8*)&Bls[nr * LS + quad * 8];
        }
        #pragma unroll
        for (int i = 0; i < 4; ++i)
            #pragma unroll
            for (int j = 0; j < 4; ++j) {
                acc[i][j] = __builtin_amdgcn_mfma_f32_16x16x32_f16(af[i], bhf[j], acc[i][j], 0, 0, 0);
                acc[i][j] = __builtin_amdgcn_mfma_f32_16x16x32_f16(af[i], blf[j], acc[i][j], 0, 0, 0);
            }
        __syncthreads();
    }

    #pragma unroll
    for (int j = 0; j < 4; ++j) {
        int n = wn * 64 + j * 16 + l16;
        float bb = 0.f;
        if (FUSE_BIAS_ELU) bb = bias[blockIdx.z * biasZ + n];
        #pragma unroll
        for (int i = 0; i < 4; ++i)
            #pragma unroll
            for (int r = 0; r < 4; ++r) {
                int m = m0 + wm * 64 + i * 16 + quad * 4 + r;
                if (m < M) {
                    float v = acc[i][j][r];
                    if (FUSE_BIAS_ELU) v = elu(v + bb);
                    Cb[(size_t)m * ldc + n] = (_Float16)v;
                }
            }
    }
}

// ============ fold attention vectors: w_s[h,k] = sum_c att_src[h,c] * W1[h*128+c, k] ============
__global__ __launch_bounds__(128) void k_wvec(const float* __restrict__ W1,
                                              const float* __restrict__ as1,
                                              const float* __restrict__ ad1,
                                              float* __restrict__ w_s,
                                              float* __restrict__ w_d)
{
    int h = blockIdx.x, k = threadIdx.x;
    float s = 0.f, d = 0.f;
    for (int c = 0; c < 128; ++c) {
        float w = W1[((size_t)(h * 128 + c)) * 128 + k];
        s += as1[h * 128 + c] * w;
        d += ad1[h * 128 + c] * w;
    }
    w_s[h * 128 + k] = s;
    w_d[h * 128 + k] = d;
}

// ============ layer-1 attention logits from raw x; also emit x as fp16 ============
__global__ __launch_bounds__(256) void k_attn_x(const float* __restrict__ x,
                                                const float* __restrict__ w_s,
                                                const float* __restrict__ w_d,
                                                float* __restrict__ a_s,
                                                float* __restrict__ a_d,
                                                _Float16* __restrict__ xh, int N)
{
    int n = blockIdx.x * 4 + (threadIdx.x >> 6);
    if (n >= N) return;
    int lane = threadIdx.x & 63;
    float2 xv = *(const float2*)(x + (size_t)n * 128 + lane * 2);
    f16x2 hv = { (_Float16)xv.x, (_Float16)xv.y };
    *(f16x2*)(xh + (size_t)n * 128 + lane * 2) = hv;
    float ps[4], pd[4];
    #pragma unroll
    for (int h = 0; h < 4; ++h) {
        float2 sv = *(const float2*)(w_s + h * 128 + lane * 2);
        float2 dv = *(const float2*)(w_d + h * 128 + lane * 2);
        ps[h] = xv.x * sv.x + xv.y * sv.y;
        pd[h] = xv.x * dv.x + xv.y * dv.y;
    }
    #pragma unroll
    for (int h = 0; h < 4; ++h)
        for (int off = 32; off; off >>= 1) {
            ps[h] += __shfl_xor(ps[h], off);
            pd[h] += __shfl_xor(pd[h], off);
        }
    if (lane == 0) {
        *(float4*)(a_s + (size_t)n * 4) = make_float4(ps[0], ps[1], ps[2], ps[3]);
        *(float4*)(a_d + (size_t)n * 4) = make_float4(pd[0], pd[1], pd[2], pd[3]);
    }
}

// ============ layer-2 attention logits from fp16 xh2 ============
__global__ __launch_bounds__(256) void k_attn2(const _Float16* __restrict__ xh,
                                               const float* __restrict__ as2,
                                               const float* __restrict__ ad2,
                                               float* __restrict__ a_s,
                                               float* __restrict__ a_d, int N)
{
    int n = blockIdx.x * 4 + (threadIdx.x >> 6);
    if (n >= N) return;
    int lane = threadIdx.x & 63;
    f16x2 xv = *(const f16x2*)(xh + (size_t)n * 128 + lane * 2);
    float vx = (float)xv.x, vy = (float)xv.y;
    float2 sv = *(const float2*)(as2 + lane * 2);
    float2 dv = *(const float2*)(ad2 + lane * 2);
    float ps = vx * sv.x + vy * sv.y;
    float pd = vx * dv.x + vy * dv.y;
    for (int off = 32; off; off >>= 1) { ps += __shfl_xor(ps, off); pd += __shfl_xor(pd, off); }
    if (lane == 0) { a_s[n] = ps; a_d[n] = pd; }
}

// ============ CSR construction ============
__global__ void k_count(const int* __restrict__ ei, int* __restrict__ deg, int E, int Ep)
{
    int e = blockIdx.x * blockDim.x + threadIdx.x;
    if (e >= Ep) return;
    int dst = (e < E) ? ei[E + e] : (e - E);
    atomicAdd(&deg[dst], 1);
}

__global__ __launch_bounds__(1024) void k_scanA(const int* __restrict__ deg,
                                                int* __restrict__ start,
                                                int* __restrict__ sums, int Ntot, int N)
{
    __shared__ int sm[1024];
    int tid = threadIdx.x;
    int i = blockIdx.x * 1024 + tid;
    int v = (i < N) ? deg[i] : 0;
    sm[tid] = v; __syncthreads();
    for (int off = 1; off < 1024; off <<= 1) {
        int t = (tid >= off) ? sm[tid - off] : 0;
        __syncthreads();
        sm[tid] += t;
        __syncthreads();
    }
    if (i < Ntot) start[i] = sm[tid] - v;
    if (tid == 1023) sums[blockIdx.x] = sm[1023];
}

__global__ void k_scanB(int* sums, int nb)
{
    int l = threadIdx.x;
    int v = (l < nb) ? sums[l] : 0;
    int orig = v;
    for (int off = 1; off < 64; off <<= 1) { int t = __shfl_up(v, off); if (l >= off) v += t; }
    if (l < nb) sums[l] = v - orig;
}

__global__ __launch_bounds__(1024) void k_scanC(int* __restrict__ start,
                                                const int* __restrict__ sums, int Ntot)
{
    int i = blockIdx.x * 1024 + threadIdx.x;
    if (i < Ntot) start[i] += sums[blockIdx.x];
}

__global__ void k_fill(const int* __restrict__ ei, const int* __restrict__ start,
                       int* __restrict__ cursor, int* __restrict__ csr_src, int E, int Ep)
{
    int e = blockIdx.x * blockDim.x + threadIdx.x;
    if (e >= Ep) return;
    int src, dst;
    if (e < E) { src = ei[e]; dst = ei[E + e]; } else { src = dst = e - E; }
    int pos = atomicAdd(&cursor[dst], 1);
    csr_src[start[dst] + pos] = src;
}

// ============ layer-1 gather: one WAVE per dst, zero barriers/LDS ============
// Edges in 64-chunks: lane computes its edge's 4-head alpha (exp once, registers),
// wave iterates chunk via __shfl broadcasts; normalize accumulator at the end.
__global__ __launch_bounds__(256) void k_gat1(const int* __restrict__ start,
                                              const int* __restrict__ csr,
                                              const float* __restrict__ a_s,
                                              const float* __restrict__ a_d,
                                              const _Float16* __restrict__ x,
                                              _Float16* __restrict__ agg, int N)
{
    int d = blockIdx.x * 4 + (threadIdx.x >> 6);
    if (d >= N) return;
    int lane = threadIdx.x & 63;
    int beg = start[d], end = start[d + 1];
    float4 ad4 = *(const float4*)(a_d + (size_t)d * 4);

    float sum0 = 0.f, sum1 = 0.f, sum2 = 0.f, sum3 = 0.f;
    float a00 = 0.f, a01 = 0.f, a10 = 0.f, a11 = 0.f;
    float a20 = 0.f, a21 = 0.f, a30 = 0.f, a31 = 0.f;
    const _Float16* xb = x + 2 * lane;

    for (int chunk = beg; chunk < end; chunk += 64) {
        int nchunk = end - chunk; if (nchunk > 64) nchunk = 64;
        int s = 0;
        float e0 = 0.f, e1 = 0.f, e2 = 0.f, e3 = 0.f;
        if (lane < nchunk) {
            s = csr[chunk + lane];
            float4 as4 = *(const float4*)(a_s + (size_t)s * 4);
            e0 = __expf(leaky(as4.x + ad4.x));
            e1 = __expf(leaky(as4.y + ad4.y));
            e2 = __expf(leaky(as4.z + ad4.z));
            e3 = __expf(leaky(as4.w + ad4.w));
            sum0 += e0; sum1 += e1; sum2 += e2; sum3 += e3;
        }
        for (int i = 0; i < nchunk; ++i) {
            int   si = __shfl(s,  i);
            float w0 = __shfl(e0, i);
            float w1 = __shfl(e1, i);
            float w2 = __shfl(e2, i);
            float w3 = __shfl(e3, i);
            f16x2 hv = *(const f16x2*)(xb + (size_t)si * 128);
            float vx = (float)hv.x, vy = (float)hv.y;
            a00 += w0 * vx; a01 += w0 * vy;
            a10 += w1 * vx; a11 += w1 * vy;
            a20 += w2 * vx; a21 += w2 * vy;
            a30 += w3 * vx; a31 += w3 * vy;
        }
    }
    #pragma unroll
    for (int o = 32; o; o >>= 1) {
        sum0 += __shfl_xor(sum0, o); sum1 += __shfl_xor(sum1, o);
        sum2 += __shfl_xor(sum2, o); sum3 += __shfl_xor(sum3, o);
    }
    float i0 = 1.f / (sum0 + 1e-16f), i1 = 1.f / (sum1 + 1e-16f);
    float i2 = 1.f / (sum2 + 1e-16f), i3 = 1.f / (sum3 + 1e-16f);
    _Float16* o = agg + (size_t)d * 512 + 2 * lane;
    f16x2 o0 = {(_Float16)(a00 * i0), (_Float16)(a01 * i0)};
    f16x2 o1 = {(_Float16)(a10 * i1), (_Float16)(a11 * i1)};
    f16x2 o2 = {(_Float16)(a20 * i2), (_Float16)(a21 * i2)};
    f16x2 o3 = {(_Float16)(a30 * i3), (_Float16)(a31 * i3)};
    *(f16x2*)(o)       = o0;
    *(f16x2*)(o + 128) = o1;
    *(f16x2*)(o + 256) = o2;
    *(f16x2*)(o + 384) = o3;
}

// ============ layer-2 gather (1 head) + bias + ELU -> h2 f32, wave per dst ============
__global__ __launch_bounds__(256) void k_gat2(const int* __restrict__ start,
                                              const int* __restrict__ csr,
                                              const float* __restrict__ a_s,
                                              const float* __restrict__ a_d,
                                              const _Float16* __restrict__ xh2,
                                              const float* __restrict__ b2,
                                              float* __restrict__ h2, int N)
{
    int d = blockIdx.x * 4 + (threadIdx.x >> 6);
    if (d >= N) return;
    int lane = threadIdx.x & 63;
    int beg = start[d], end = start[d + 1];
    float ad = a_d[d];

    float sum = 0.f, ax = 0.f, ay = 0.f;
    const _Float16* xb = xh2 + 2 * lane;

    for (int chunk = beg; chunk < end; chunk += 64) {
        int nchunk = end - chunk; if (nchunk > 64) nchunk = 64;
        int s = 0; float e = 0.f;
        if (lane < nchunk) {
            s = csr[chunk + lane];
            e = __expf(leaky(a_s[s] + ad));
            sum += e;
        }
        for (int i = 0; i < nchunk; ++i) {
            int   si = __shfl(s, i);
            float w  = __shfl(e, i);
            f16x2 hv = *(const f16x2*)(xb + (size_t)si * 128);
            ax += w * (float)hv.x;
            ay += w * (float)hv.y;
        }
    }
    #pragma unroll
    for (int o = 32; o; o >>= 1) sum += __shfl_xor(sum, o);
    float inv = 1.f / (sum + 1e-16f);
    float2 bb = *(const float2*)(b2 + 2 * lane);
    float2 ov = make_float2(elu(ax * inv + bb.x), elu(ay * inv + bb.y));
    *(float2*)(h2 + (size_t)d * 128 + 2 * lane) = ov;
}

// ============ graph boundaries from SORTED batch ============
__global__ void k_gbound(const int* __restrict__ batch, int* __restrict__ gstart, int N, int G)
{
    int n = blockIdx.x * blockDim.x + threadIdx.x;
    if (n >= N) return;
    int b = batch[n];
    int prev = (n == 0) ? -1 : batch[n - 1];
    for (int g = prev + 1; g <= b; ++g) gstart[g] = n;
    if (n == N - 1)
        for (int g = b + 1; g <= G; ++g) gstart[g] = N;
}

// ============ pooling stage A: chunked partial sums ============
#define PCH 64
__global__ __launch_bounds__(128) void k_poolA(const float* __restrict__ h2,
                                               const int* __restrict__ batch,
                                               float* __restrict__ pooled, int N)
{
    int c = threadIdx.x;
    int n0 = blockIdx.x * PCH;
    int n1 = n0 + PCH < N ? n0 + PCH : N;
    if (n0 >= N) return;
    int g = batch[n0];
    float acc = 0.f;
    for (int n = n0; n < n1; ++n) {
        int bg = batch[n];
        if (bg != g) { atomicAdd(&pooled[(size_t)g * 128 + c], acc); acc = 0.f; g = bg; }
        acc += h2[(size_t)n * 128 + c];
    }
    atomicAdd(&pooled[(size_t)g * 128 + c], acc);
}

// ============ head: mean + relu(pooled@Wh1^T+bh1) @ Wh2^T + bh2 ============
__global__ __launch_bounds__(128) void k_head(const float* __restrict__ pooled,
                                              const int* __restrict__ gstart,
                                              const float* __restrict__ Wh1,
                                              const float* __restrict__ bh1,
                                              const float* __restrict__ Wh2,
                                              const float* __restrict__ bh2,
                                              float* __restrict__ out)
{
    int g = blockIdx.x, c = threadIdx.x;
    __shared__ float p[128];
    __shared__ float red[128];
    float cf = (float)(gstart[g + 1] - gstart[g]); cf = cf > 1.f ? cf : 1.f;
    p[c] = pooled[(size_t)g * 128 + c] / cf;
    __syncthreads();
    float z = bh1[c];
    for (int k = 0; k < 128; ++k) z += p[k] * Wh1[c * 128 + k];
    z = z > 0.f ? z : 0.f;
    red[c] = z * Wh2[c];
    __syncthreads();
    for (int st = 64; st > 0; st >>= 1) { if (c < st) red[c] += red[c + st]; __syncthreads(); }
    if (c == 0) out[g] = red[0] + bh2[0];
}

// ============ launch ============
extern "C" void kernel_launch(void* const* d_in, const int* in_sizes, int n_in,
                              void* d_out, int out_size, void* d_ws, size_t ws_size,
                              hipStream_t stream)
{
    const float* x   = (const float*)d_in[0];
    const int*   ei  = (const int*)d_in[1];
    const int*   bat = (const int*)d_in[2];
    const float* W1  = (const float*)d_in[3];
    const float* as1 = (const float*)d_in[4];
    const float* ad1 = (const float*)d_in[5];
    const float* b1  = (const float*)d_in[6];
    const float* W2  = (const float*)d_in[7];
    const float* as2 = (const float*)d_in[8];
    const float* ad2 = (const float*)d_in[9];
    const float* b2  = (const float*)d_in[10];
    const float* Wh1 = (const float*)d_in[11];
    const float* bh1 = (const float*)d_in[12];
    const float* Wh2 = (const float*)d_in[13];
    const float* bh2 = (const float*)d_in[14];
    float* out = (float*)d_out;

    const int N  = in_sizes[0] / 128;
    const int E  = in_sizes[1] / 2;
    const int Ep = E + N;
    const int G  = 128;

    char* w = (char*)d_ws;
    size_t off = 0;
    auto alloc = [&](size_t bytes) -> char* {
        char* p = w + off; off += (bytes + 511) & ~(size_t)511; return p;
    };
    _Float16* x_h  = (_Float16*)alloc((size_t)N * 128 * 2);
    _Float16* agg  = (_Float16*)alloc((size_t)N * 512 * 2);
    _Float16* h1   = (_Float16*)alloc((size_t)N * 512 * 2);
    _Float16* xh2h = (_Float16*)alloc((size_t)N * 128 * 2);
    float*    h2   = (float*)alloc((size_t)N * 128 * 4);
    float*    As1  = (float*)alloc((size_t)N * 4 * 4);
    float*    Ad1  = (float*)alloc((size_t)N * 4 * 4);
    float*    As2  = (float*)alloc((size_t)N * 4);
    float*    Ad2  = (float*)alloc((size_t)N * 4);
    float*    w_s1 = (float*)alloc(512 * 4);
    float*    w_d1 = (float*)alloc(512 * 4);
    _Float16* W1hi = (_Float16*)alloc(65536 * 2);
    _Float16* W1lo = (_Float16*)alloc(65536 * 2);
    _Float16* W2hi = (_Float16*)alloc(65536 * 2);
    _Float16* W2lo = (_Float16*)alloc(65536 * 2);
    int* startb = (int*)alloc((size_t)(N + 1) * 4);
    int* csr    = (int*)alloc((size_t)Ep * 4);
    int* sums   = (int*)alloc(4096);
    int* gstart = (int*)alloc((size_t)(G + 1) * 4);
    char* zbase = w + off;                                // zero-init group
    int*   deg    = (int*)alloc((size_t)N * 4);
    int*   cursor = (int*)alloc((size_t)N * 4);
    float* pooled = (float*)alloc((size_t)G * 128 * 4);
    size_t zbytes = (size_t)((w + off) - zbase);

    hipMemsetAsync(zbase, 0, zbytes, stream);

    // 1) fold attention vectors; logits + fp16 x
    k_wvec<<<4, 128, 0, stream>>>(W1, as1, ad1, w_s1, w_d1);
    k_attn_x<<<(N + 3) / 4, 256, 0, stream>>>(x, w_s1, w_d1, As1, Ad1, x_h, N);
    // 2) weights -> split fp16
    k_wcvt<<<256, 256, 0, stream>>>(W1, W1hi, W1lo, 65536);
    k_wcvt<<<256, 256, 0, stream>>>(W2, W2hi, W2lo, 65536);
    // 3) CSR by destination (self-loops appended)
    k_count<<<(Ep + 255) / 256, 256, 0, stream>>>(ei, deg, E, Ep);
    int nb = (N + 1 + 1023) / 1024;
    k_scanA<<<nb, 1024, 0, stream>>>(deg, startb, sums, N + 1, N);
    k_scanB<<<1, 64, 0, stream>>>(sums, nb);
    k_scanC<<<nb, 1024, 0, stream>>>(startb, sums, N + 1);
    k_fill<<<(Ep + 255) / 256, 256, 0, stream>>>(ei, startb, cursor, csr, E, Ep);
    // 4) graph boundaries
    k_gbound<<<(N + 255) / 256, 256, 0, stream>>>(bat, gstart, N, G);
    // 5) layer-1 gather (wave per dst) -> agg fp16 [N, 4*128]
    k_gat1<<<(N + 3) / 4, 256, 0, stream>>>(startb, csr, As1, Ad1, x_h, agg, N);
    // 6) block-diag projection + bias + ELU (fp16 MFMA): h1_h = elu(agg_h @ W1_h^T + b1_h)
    k_gemm_h<true><<<dim3((N + 127) / 128, 1, 4), 256, 0, stream>>>(
        agg, W1hi, W1lo, b1, h1, N, 128, 512, 128, 512, 128L, 16384L, 128L, 128L);
    // 7) xh2 = h1 @ W2^T  [N,128]  (fp16 MFMA)
    k_gemm_h<false><<<dim3((N + 127) / 128, 1, 1), 256, 0, stream>>>(
        h1, W2hi, W2lo, nullptr, xh2h, N, 512, 512, 512, 128, 0L, 0L, 0L, 0L);
    // 8) layer-2 attention logits
    k_attn2<<<(N + 3) / 4, 256, 0, stream>>>(xh2h, as2, ad2, As2, Ad2, N);
    // 9) layer-2 gather + bias + ELU -> h2 f32 (wave per dst)
    k_gat2<<<(N + 3) / 4, 256, 0, stream>>>(startb, csr, As2, Ad2, xh2h, b2, h2, N);
    // 10) two-stage pooling + MLP head
    k_poolA<<<(N + PCH - 1) / PCH, 128, 0, stream>>>(h2, bat, pooled, N);
    k_head<<<G, 128, 0, stream>>>(pooled, gstart, Wh1, bh1, Wh2, bh2, out);
}